// Round 1
// baseline (2809.758 us; speedup 1.0000x reference)
//
#include <hip/hip_runtime.h>
#include <cstddef>

#define L_SEQ 1024
#define B_SZ  128
#define D_SZ  256
#define H_SZ  256

// ---------------------------------------------------------------------------
// Kernel 1: xproj[m,n] = sum_d x[m,d] * Wx[n,d] + bx[n]
//   M = L*B = 131072, K = D = 256, N = H = 256
//   64x64 block tile, 256 threads, 4x4 micro-tile, K-tile = 16,
//   LDS tiles stored k-major (transposed) so inner reads are float4.
//   Output goes straight into d_out's hAll region.
// ---------------------------------------------------------------------------
#define KT  16
#define LDP 68   // padded leading dim (floats); 68*4B = 17*16B keeps float4 align

__global__ __launch_bounds__(256) void xproj_gemm(
    const float* __restrict__ x, const float* __restrict__ Wx,
    const float* __restrict__ bx, float* __restrict__ out)
{
    __shared__ float sA[KT][LDP];
    __shared__ float sB[KT][LDP];

    const int tm  = blockIdx.x;        // M tile (0..2047)
    const int tn  = blockIdx.y;        // N tile (0..3)
    const int tid = threadIdx.x;
    const int tx  = tid & 15;          // n quad
    const int ty  = tid >> 4;          // m quad
    const int srow = tid >> 2;         // staging row (0..63)
    const int skq  = tid & 3;          // staging k quad (0..3)

    const float* __restrict__ Ag = x  + (size_t)(tm * 64 + srow) * D_SZ + skq * 4;
    const float* __restrict__ Bg = Wx + (size_t)(tn * 64 + srow) * D_SZ + skq * 4;

    float c[4][4];
    #pragma unroll
    for (int i = 0; i < 4; ++i)
        #pragma unroll
        for (int j = 0; j < 4; ++j) c[i][j] = 0.0f;

    for (int kt = 0; kt < D_SZ / KT; ++kt) {
        float4 av = *reinterpret_cast<const float4*>(Ag + kt * KT);
        float4 bv = *reinterpret_cast<const float4*>(Bg + kt * KT);
        __syncthreads();   // protect previous iteration's reads
        sA[skq * 4 + 0][srow] = av.x; sA[skq * 4 + 1][srow] = av.y;
        sA[skq * 4 + 2][srow] = av.z; sA[skq * 4 + 3][srow] = av.w;
        sB[skq * 4 + 0][srow] = bv.x; sB[skq * 4 + 1][srow] = bv.y;
        sB[skq * 4 + 2][srow] = bv.z; sB[skq * 4 + 3][srow] = bv.w;
        __syncthreads();
        #pragma unroll
        for (int kk = 0; kk < KT; ++kk) {
            float4 a = *reinterpret_cast<const float4*>(&sA[kk][ty * 4]);
            float4 b = *reinterpret_cast<const float4*>(&sB[kk][tx * 4]);
            float aa[4] = {a.x, a.y, a.z, a.w};
            float bb[4] = {b.x, b.y, b.z, b.w};
            #pragma unroll
            for (int i = 0; i < 4; ++i)
                #pragma unroll
                for (int j = 0; j < 4; ++j)
                    c[i][j] = fmaf(aa[i], bb[j], c[i][j]);
        }
    }

    float4 bias = *reinterpret_cast<const float4*>(bx + tn * 64 + tx * 4);
    #pragma unroll
    for (int i = 0; i < 4; ++i) {
        float4 v;
        v.x = c[i][0] + bias.x;
        v.y = c[i][1] + bias.y;
        v.z = c[i][2] + bias.z;
        v.w = c[i][3] + bias.w;
        *reinterpret_cast<float4*>(
            out + (size_t)(tm * 64 + ty * 4 + i) * H_SZ + tn * 64 + tx * 4) = v;
    }
}

// ---------------------------------------------------------------------------
// Kernel 2: serial scan. One block per batch row b (128 blocks, 256 threads).
// Thread j owns output channel j and keeps Wh row j (256 fp32) in registers.
// h state double-buffered in LDS; xp[t] prefetched one step ahead; h[t]
// overwrites xproj[t] in place in d_out.
// ---------------------------------------------------------------------------
__global__ __launch_bounds__(256, 1) void rnn_scan(
    const float* __restrict__ h0, const float* __restrict__ Wh,
    const float* __restrict__ bh, float* __restrict__ out)
{
    __shared__ __align__(16) float hbuf[2][H_SZ];
    const int b = blockIdx.x;
    const int j = threadIdx.x;

    // Load Wh row j into registers (one-time; L2-shared across blocks).
    float w[H_SZ];
    {
        const float4* wrow = reinterpret_cast<const float4*>(Wh + (size_t)j * H_SZ);
        #pragma unroll
        for (int q = 0; q < H_SZ / 4; ++q) {
            float4 v = wrow[q];
            w[4 * q + 0] = v.x; w[4 * q + 1] = v.y;
            w[4 * q + 2] = v.z; w[4 * q + 3] = v.w;
        }
    }
    const float bj = bh[j];
    hbuf[0][j] = h0[(size_t)b * H_SZ + j];
    __syncthreads();

    float* __restrict__ outb = out + (size_t)b * H_SZ + j;
    const size_t tstride = (size_t)B_SZ * H_SZ;

    float xp = outb[0];   // xproj at t=0
    float hn = 0.0f;
    int cur = 0;
    for (int t = 0; t < L_SEQ; ++t) {
        // Prefetch next step's xproj (at t = L-1 this reads the h_final
        // region -- in bounds, value discarded).
        float xp_next = outb[(size_t)(t + 1) * tstride];

        float a0 = 0.f, a1 = 0.f, a2 = 0.f, a3 = 0.f;
        const float4* hv4 = reinterpret_cast<const float4*>(hbuf[cur]);
        #pragma unroll
        for (int q = 0; q < H_SZ / 4; ++q) {
            float4 hv = hv4[q];   // same-address broadcast read across lanes
            a0 = fmaf(w[4 * q + 0], hv.x, a0);
            a1 = fmaf(w[4 * q + 1], hv.y, a1);
            a2 = fmaf(w[4 * q + 2], hv.z, a2);
            a3 = fmaf(w[4 * q + 3], hv.w, a3);
        }
        float pre = xp + bj + ((a0 + a1) + (a2 + a3));
        // tanh(x) = 1 - 2/(exp(2x)+1); exp via v_exp_f32, div via v_rcp_f32.
        float e  = __expf(2.0f * pre);
        hn = 1.0f - 2.0f * __builtin_amdgcn_rcpf(e + 1.0f);

        outb[(size_t)t * tstride] = hn;   // hAll[t,b,j] (overwrites xproj)
        hbuf[cur ^ 1][j] = hn;
        __syncthreads();
        cur ^= 1;
        xp = xp_next;
    }
    // h_final
    out[(size_t)L_SEQ * tstride + (size_t)b * H_SZ + j] = hn;
}

extern "C" void kernel_launch(void* const* d_in, const int* in_sizes, int n_in,
                              void* d_out, int out_size, void* d_ws, size_t ws_size,
                              hipStream_t stream) {
    const float* x    = (const float*)d_in[0];   // [L,B,D]
    const float* h0   = (const float*)d_in[1];   // [B,H]
    const float* Wx_w = (const float*)d_in[2];   // [H,D]
    const float* Wx_b = (const float*)d_in[3];   // [H]
    const float* Wh_w = (const float*)d_in[4];   // [H,H]
    const float* Wh_b = (const float*)d_in[5];   // [H]
    float* out = (float*)d_out;                  // [L,B,H] ++ [B,H]

    (void)in_sizes; (void)n_in; (void)d_ws; (void)ws_size; (void)out_size;

    // xproj -> d_out[0 : L*B*H]
    dim3 grid1((L_SEQ * B_SZ) / 64, H_SZ / 64);
    xproj_gemm<<<grid1, 256, 0, stream>>>(x, Wx_w, Wx_b, out);

    // serial scan, in place
    rnn_scan<<<dim3(B_SZ), 256, 0, stream>>>(h0, Wh_w, Wh_b, out);
}

// Round 2
// 1205.802 us; speedup vs baseline: 2.3302x; 2.3302x over previous
//
#include <hip/hip_runtime.h>
#include <cstddef>

#define L_SEQ 1024
#define B_SZ  128
#define D_SZ  256
#define H_SZ  256

// ---------------------------------------------------------------------------
// Kernel 1: xproj[m,n] = sum_d x[m,d] * Wx[n,d] + bx[n]   (unchanged from R1)
// ---------------------------------------------------------------------------
#define KT  16
#define LDP 68

__global__ __launch_bounds__(256) void xproj_gemm(
    const float* __restrict__ x, const float* __restrict__ Wx,
    const float* __restrict__ bx, float* __restrict__ out)
{
    __shared__ float sA[KT][LDP];
    __shared__ float sB[KT][LDP];

    const int tm  = blockIdx.x;
    const int tn  = blockIdx.y;
    const int tid = threadIdx.x;
    const int tx  = tid & 15;
    const int ty  = tid >> 4;
    const int srow = tid >> 2;
    const int skq  = tid & 3;

    const float* __restrict__ Ag = x  + (size_t)(tm * 64 + srow) * D_SZ + skq * 4;
    const float* __restrict__ Bg = Wx + (size_t)(tn * 64 + srow) * D_SZ + skq * 4;

    float c[4][4];
    #pragma unroll
    for (int i = 0; i < 4; ++i)
        #pragma unroll
        for (int j = 0; j < 4; ++j) c[i][j] = 0.0f;

    for (int kt = 0; kt < D_SZ / KT; ++kt) {
        float4 av = *reinterpret_cast<const float4*>(Ag + kt * KT);
        float4 bv = *reinterpret_cast<const float4*>(Bg + kt * KT);
        __syncthreads();
        sA[skq * 4 + 0][srow] = av.x; sA[skq * 4 + 1][srow] = av.y;
        sA[skq * 4 + 2][srow] = av.z; sA[skq * 4 + 3][srow] = av.w;
        sB[skq * 4 + 0][srow] = bv.x; sB[skq * 4 + 1][srow] = bv.y;
        sB[skq * 4 + 2][srow] = bv.z; sB[skq * 4 + 3][srow] = bv.w;
        __syncthreads();
        #pragma unroll
        for (int kk = 0; kk < KT; ++kk) {
            float4 a = *reinterpret_cast<const float4*>(&sA[kk][ty * 4]);
            float4 b = *reinterpret_cast<const float4*>(&sB[kk][tx * 4]);
            float aa[4] = {a.x, a.y, a.z, a.w};
            float bb[4] = {b.x, b.y, b.z, b.w};
            #pragma unroll
            for (int i = 0; i < 4; ++i)
                #pragma unroll
                for (int j = 0; j < 4; ++j)
                    c[i][j] = fmaf(aa[i], bb[j], c[i][j]);
        }
    }

    float4 bias = *reinterpret_cast<const float4*>(bx + tn * 64 + tx * 4);
    #pragma unroll
    for (int i = 0; i < 4; ++i) {
        float4 v;
        v.x = c[i][0] + bias.x;
        v.y = c[i][1] + bias.y;
        v.z = c[i][2] + bias.z;
        v.w = c[i][3] + bias.w;
        *reinterpret_cast<float4*>(
            out + (size_t)(tm * 64 + ty * 4 + i) * H_SZ + tn * 64 + tx * 4) = v;
    }
}

// ---------------------------------------------------------------------------
// Kernel 2: serial scan, v2.
// 128 blocks (one per batch row) x 512 threads (8 waves).
// Thread layout: kslice = lane&7 (8-way K split, 32 K-elems each),
//                jg = wave*8 + (lane>>3) (channel group 0..63).
// Each thread owns channels jg+{0,64,128,192}: w = 4 arrays of 32 floats
// (SROA-friendly, ~128 VGPRs). 128 FMAs/thread/step.
// h in LDS, double-buffered, padded layout: slice s at word s*40 (16B-aligned,
// 2-way bank aliasing only = free). 8 ds_read_b128/thread/step.
// Reduction over 8 kslices: xor1/xor2 via DPP quad-perm adds (VALU pipe),
// xor4 via one ds_swizzle per accumulator.
// ---------------------------------------------------------------------------
#define SLICE_W 40   // padded words per 32-float K-slice (160B, float4-aligned)

template <int CTRL>
__device__ __forceinline__ float dpp_add(float v) {
    int y = __builtin_amdgcn_mov_dpp(__float_as_int(v), CTRL, 0xf, 0xf, true);
    return v + __int_as_float(y);
}
__device__ __forceinline__ float swz_xor4_add(float v) {
    int y = __builtin_amdgcn_ds_swizzle(__float_as_int(v), 0x101F); // xor 4
    return v + __int_as_float(y);
}
__device__ __forceinline__ float red8(float v) {
    v = dpp_add<0xB1>(v);   // quad_perm [1,0,3,2]  (xor 1)
    v = dpp_add<0x4E>(v);   // quad_perm [2,3,0,1]  (xor 2)
    v = swz_xor4_add(v);    // xor 4 across quads
    return v;
}
__device__ __forceinline__ float fast_tanh(float x) {
    float e = __expf(2.0f * x);
    return 1.0f - 2.0f * __builtin_amdgcn_rcpf(e + 1.0f);
}

__global__ __launch_bounds__(512, 2) void rnn_scan(
    const float* __restrict__ h0, const float* __restrict__ Wh,
    const float* __restrict__ bh, float* __restrict__ out)
{
    __shared__ __align__(16) float hs[2][8 * SLICE_W];

    const int b    = blockIdx.x;
    const int tid  = threadIdx.x;
    const int lane = tid & 63;
    const int wave = tid >> 6;
    const int ks   = lane & 7;                 // K slice 0..7
    const int jg   = wave * 8 + (lane >> 3);   // channel group 0..63

    // --- load weights: 4 channels x 32 K-elems into registers ---
    float w0[32], w1[32], w2[32], w3[32];
    {
        const float4* r0 = reinterpret_cast<const float4*>(Wh + (size_t)(jg +   0) * H_SZ + ks * 32);
        const float4* r1 = reinterpret_cast<const float4*>(Wh + (size_t)(jg +  64) * H_SZ + ks * 32);
        const float4* r2 = reinterpret_cast<const float4*>(Wh + (size_t)(jg + 128) * H_SZ + ks * 32);
        const float4* r3 = reinterpret_cast<const float4*>(Wh + (size_t)(jg + 192) * H_SZ + ks * 32);
        #pragma unroll
        for (int q = 0; q < 8; ++q) {
            float4 v;
            v = r0[q]; w0[4*q+0]=v.x; w0[4*q+1]=v.y; w0[4*q+2]=v.z; w0[4*q+3]=v.w;
            v = r1[q]; w1[4*q+0]=v.x; w1[4*q+1]=v.y; w1[4*q+2]=v.z; w1[4*q+3]=v.w;
            v = r2[q]; w2[4*q+0]=v.x; w2[4*q+1]=v.y; w2[4*q+2]=v.z; w2[4*q+3]=v.w;
            v = r3[q]; w3[4*q+0]=v.x; w3[4*q+1]=v.y; w3[4*q+2]=v.z; w3[4*q+3]=v.w;
        }
    }
    const float bj0 = bh[jg +   0];
    const float bj1 = bh[jg +  64];
    const float bj2 = bh[jg + 128];
    const float bj3 = bh[jg + 192];

    // --- init h state (padded layout) ---
    if (tid < H_SZ) {
        hs[0][(tid >> 5) * SLICE_W + (tid & 31)] = h0[(size_t)b * H_SZ + tid];
    }
    __syncthreads();

    float* __restrict__ outb = out + (size_t)b * H_SZ;
    const size_t tstr = (size_t)B_SZ * H_SZ;

    float xp0 = outb[jg +   0];
    float xp1 = outb[jg +  64];
    float xp2 = outb[jg + 128];
    float xp3 = outb[jg + 192];

    float hn0 = 0.f, hn1 = 0.f, hn2 = 0.f, hn3 = 0.f;
    int cur = 0;
    for (int t = 0; t < L_SEQ; ++t) {
        // prefetch next step's xproj (t=L-1 reads the h_final region: in
        // bounds, discarded)
        const size_t nb = (size_t)(t + 1) * tstr;
        float nxp0 = outb[nb + jg +   0];
        float nxp1 = outb[nb + jg +  64];
        float nxp2 = outb[nb + jg + 128];
        float nxp3 = outb[nb + jg + 192];

        float a0 = 0.f, a1 = 0.f, a2 = 0.f, a3 = 0.f;
        const float4* hv4 = reinterpret_cast<const float4*>(&hs[cur][ks * SLICE_W]);
        #pragma unroll
        for (int q = 0; q < 8; ++q) {
            float4 hv = hv4[q];
            a0 = fmaf(w0[4*q+0], hv.x, a0); a0 = fmaf(w0[4*q+1], hv.y, a0);
            a0 = fmaf(w0[4*q+2], hv.z, a0); a0 = fmaf(w0[4*q+3], hv.w, a0);
            a1 = fmaf(w1[4*q+0], hv.x, a1); a1 = fmaf(w1[4*q+1], hv.y, a1);
            a1 = fmaf(w1[4*q+2], hv.z, a1); a1 = fmaf(w1[4*q+3], hv.w, a1);
            a2 = fmaf(w2[4*q+0], hv.x, a2); a2 = fmaf(w2[4*q+1], hv.y, a2);
            a2 = fmaf(w2[4*q+2], hv.z, a2); a2 = fmaf(w2[4*q+3], hv.w, a2);
            a3 = fmaf(w3[4*q+0], hv.x, a3); a3 = fmaf(w3[4*q+1], hv.y, a3);
            a3 = fmaf(w3[4*q+2], hv.z, a3); a3 = fmaf(w3[4*q+3], hv.w, a3);
        }
        a0 = red8(a0); a1 = red8(a1); a2 = red8(a2); a3 = red8(a3);

        hn0 = fast_tanh(xp0 + bj0 + a0);
        hn1 = fast_tanh(xp1 + bj1 + a1);
        hn2 = fast_tanh(xp2 + bj2 + a2);
        hn3 = fast_tanh(xp3 + bj3 + a3);

        if (ks == 0) {
            const size_t tb = (size_t)t * tstr;
            outb[tb + jg +   0] = hn0;
            outb[tb + jg +  64] = hn1;
            outb[tb + jg + 128] = hn2;
            outb[tb + jg + 192] = hn3;
            float* hw = hs[cur ^ 1];
            const int base = (jg >> 5) * SLICE_W + (jg & 31);
            hw[base + 0 * (2 * SLICE_W)] = hn0;
            hw[base + 1 * (2 * SLICE_W)] = hn1;
            hw[base + 2 * (2 * SLICE_W)] = hn2;
            hw[base + 3 * (2 * SLICE_W)] = hn3;
        }
        __syncthreads();
        cur ^= 1;
        xp0 = nxp0; xp1 = nxp1; xp2 = nxp2; xp3 = nxp3;
    }

    if (ks == 0) {
        float* hf = out + (size_t)L_SEQ * tstr + (size_t)b * H_SZ;
        hf[jg +   0] = hn0;
        hf[jg +  64] = hn1;
        hf[jg + 128] = hn2;
        hf[jg + 192] = hn3;
    }
}

extern "C" void kernel_launch(void* const* d_in, const int* in_sizes, int n_in,
                              void* d_out, int out_size, void* d_ws, size_t ws_size,
                              hipStream_t stream) {
    const float* x    = (const float*)d_in[0];   // [L,B,D]
    const float* h0   = (const float*)d_in[1];   // [B,H]
    const float* Wx_w = (const float*)d_in[2];   // [H,D]
    const float* Wx_b = (const float*)d_in[3];   // [H]
    const float* Wh_w = (const float*)d_in[4];   // [H,H]
    const float* Wh_b = (const float*)d_in[5];   // [H]
    float* out = (float*)d_out;                  // [L,B,H] ++ [B,H]

    (void)in_sizes; (void)n_in; (void)d_ws; (void)ws_size; (void)out_size;

    dim3 grid1((L_SEQ * B_SZ) / 64, H_SZ / 64);
    xproj_gemm<<<grid1, 256, 0, stream>>>(x, Wx_w, Wx_b, out);

    rnn_scan<<<dim3(B_SZ), 512, 0, stream>>>(h0, Wh_w, Wh_b, out);
}

// Round 3
// 1122.439 us; speedup vs baseline: 2.5033x; 1.0743x over previous
//
#include <hip/hip_runtime.h>
#include <cstddef>

#define L_SEQ 1024
#define B_SZ  128
#define D_SZ  256
#define H_SZ  256

// ---------------------------------------------------------------------------
// Kernel 1: xproj[m,n] = sum_d x[m,d] * Wx[n,d] + bx[n]
//   v2: 128x128 block tile, 256 threads, 8x8 micro-tile as 2x2 chunks of 4x4
//   (n-chunks at tx*4 and 64+tx*4 -> <=2-way LDS bank aliasing, free).
//   4 ds_read_b128 per 64 FMAs -> VALU-bound, not DS-bound.
// ---------------------------------------------------------------------------
#define KT  16
#define LDA 132   // 128 + 4 pad

__global__ __launch_bounds__(256) void xproj_gemm(
    const float* __restrict__ x, const float* __restrict__ Wx,
    const float* __restrict__ bx, float* __restrict__ out)
{
    __shared__ float sA[KT][LDA];
    __shared__ float sB[KT][LDA];

    const int tm  = blockIdx.x;        // M tile of 128 (0..1023)
    const int tn  = blockIdx.y;        // N tile of 128 (0..1)
    const int tid = threadIdx.x;
    const int tx  = tid & 15;          // n quad
    const int ty  = tid >> 4;          // m quad
    const int srow = tid >> 2;         // staging row (0..63)
    const int skq  = tid & 3;          // staging k quad (0..3)

    const float* __restrict__ Ag = x  + (size_t)(tm * 128 + srow) * D_SZ + skq * 4;
    const float* __restrict__ Bg = Wx + (size_t)(tn * 128 + srow) * D_SZ + skq * 4;

    // c[mc][nc][i][j]
    float c[2][2][4][4];
    #pragma unroll
    for (int mc = 0; mc < 2; ++mc)
        #pragma unroll
        for (int nc = 0; nc < 2; ++nc)
            #pragma unroll
            for (int i = 0; i < 4; ++i)
                #pragma unroll
                for (int j = 0; j < 4; ++j) c[mc][nc][i][j] = 0.0f;

    for (int kt = 0; kt < D_SZ / KT; ++kt) {
        float4 av0 = *reinterpret_cast<const float4*>(Ag + kt * KT);
        float4 av1 = *reinterpret_cast<const float4*>(Ag + (size_t)64 * D_SZ + kt * KT);
        float4 bv0 = *reinterpret_cast<const float4*>(Bg + kt * KT);
        float4 bv1 = *reinterpret_cast<const float4*>(Bg + (size_t)64 * D_SZ + kt * KT);
        __syncthreads();   // protect previous iteration's reads
        sA[skq * 4 + 0][srow] = av0.x; sA[skq * 4 + 1][srow] = av0.y;
        sA[skq * 4 + 2][srow] = av0.z; sA[skq * 4 + 3][srow] = av0.w;
        sA[skq * 4 + 0][64 + srow] = av1.x; sA[skq * 4 + 1][64 + srow] = av1.y;
        sA[skq * 4 + 2][64 + srow] = av1.z; sA[skq * 4 + 3][64 + srow] = av1.w;
        sB[skq * 4 + 0][srow] = bv0.x; sB[skq * 4 + 1][srow] = bv0.y;
        sB[skq * 4 + 2][srow] = bv0.z; sB[skq * 4 + 3][srow] = bv0.w;
        sB[skq * 4 + 0][64 + srow] = bv1.x; sB[skq * 4 + 1][64 + srow] = bv1.y;
        sB[skq * 4 + 2][64 + srow] = bv1.z; sB[skq * 4 + 3][64 + srow] = bv1.w;
        __syncthreads();
        #pragma unroll
        for (int kk = 0; kk < KT; ++kk) {
            float4 am0 = *reinterpret_cast<const float4*>(&sA[kk][ty * 4]);
            float4 am1 = *reinterpret_cast<const float4*>(&sA[kk][64 + ty * 4]);
            float4 bn0 = *reinterpret_cast<const float4*>(&sB[kk][tx * 4]);
            float4 bn1 = *reinterpret_cast<const float4*>(&sB[kk][64 + tx * 4]);
            float aa[2][4] = {{am0.x, am0.y, am0.z, am0.w}, {am1.x, am1.y, am1.z, am1.w}};
            float bb[2][4] = {{bn0.x, bn0.y, bn0.z, bn0.w}, {bn1.x, bn1.y, bn1.z, bn1.w}};
            #pragma unroll
            for (int mc = 0; mc < 2; ++mc)
                #pragma unroll
                for (int nc = 0; nc < 2; ++nc)
                    #pragma unroll
                    for (int i = 0; i < 4; ++i)
                        #pragma unroll
                        for (int j = 0; j < 4; ++j)
                            c[mc][nc][i][j] = fmaf(aa[mc][i], bb[nc][j], c[mc][nc][i][j]);
        }
    }

    #pragma unroll
    for (int nc = 0; nc < 2; ++nc) {
        float4 bias = *reinterpret_cast<const float4*>(bx + tn * 128 + nc * 64 + tx * 4);
        #pragma unroll
        for (int mc = 0; mc < 2; ++mc)
            #pragma unroll
            for (int i = 0; i < 4; ++i) {
                float4 v;
                v.x = c[mc][nc][i][0] + bias.x;
                v.y = c[mc][nc][i][1] + bias.y;
                v.z = c[mc][nc][i][2] + bias.z;
                v.w = c[mc][nc][i][3] + bias.w;
                *reinterpret_cast<float4*>(
                    out + (size_t)(tm * 128 + mc * 64 + ty * 4 + i) * H_SZ
                        + tn * 128 + nc * 64 + tx * 4) = v;
            }
    }
}

// ---------------------------------------------------------------------------
// Kernel 2: serial scan, v3 = v2 + amdgpu_waves_per_eu(2,2).
// Only 128 blocks exist (one per batch row) -> exactly 1 block/CU; pinning
// the occupancy target at 2 waves/EU gives the allocator the full 256-VGPR
// budget so the 128 weight floats stay in arch VGPRs (v2's 88-VGPR alloc
// re-materialized them every step -> ~800 extra cyc/step).
// ---------------------------------------------------------------------------
#define SLICE_W 40   // padded words per 32-float K-slice (160B, float4-aligned)

template <int CTRL>
__device__ __forceinline__ float dpp_add(float v) {
    int y = __builtin_amdgcn_mov_dpp(__float_as_int(v), CTRL, 0xf, 0xf, true);
    return v + __int_as_float(y);
}
__device__ __forceinline__ float swz_xor4_add(float v) {
    int y = __builtin_amdgcn_ds_swizzle(__float_as_int(v), 0x101F); // xor 4
    return v + __int_as_float(y);
}
__device__ __forceinline__ float red8(float v) {
    v = dpp_add<0xB1>(v);   // quad_perm [1,0,3,2]  (xor 1)
    v = dpp_add<0x4E>(v);   // quad_perm [2,3,0,1]  (xor 2)
    v = swz_xor4_add(v);    // xor 4 across quads
    return v;
}
__device__ __forceinline__ float fast_tanh(float x) {
    float e = __expf(2.0f * x);
    return 1.0f - 2.0f * __builtin_amdgcn_rcpf(e + 1.0f);
}

__global__ __launch_bounds__(512)
__attribute__((amdgpu_waves_per_eu(2, 2)))
void rnn_scan(
    const float* __restrict__ h0, const float* __restrict__ Wh,
    const float* __restrict__ bh, float* __restrict__ out)
{
    __shared__ __align__(16) float hs[2][8 * SLICE_W];

    const int b    = blockIdx.x;
    const int tid  = threadIdx.x;
    const int lane = tid & 63;
    const int wave = tid >> 6;
    const int ks   = lane & 7;                 // K slice 0..7
    const int jg   = wave * 8 + (lane >> 3);   // channel group 0..63

    // --- load weights: 4 channels x 32 K-elems into registers ---
    float w0[32], w1[32], w2[32], w3[32];
    {
        const float4* r0 = reinterpret_cast<const float4*>(Wh + (size_t)(jg +   0) * H_SZ + ks * 32);
        const float4* r1 = reinterpret_cast<const float4*>(Wh + (size_t)(jg +  64) * H_SZ + ks * 32);
        const float4* r2 = reinterpret_cast<const float4*>(Wh + (size_t)(jg + 128) * H_SZ + ks * 32);
        const float4* r3 = reinterpret_cast<const float4*>(Wh + (size_t)(jg + 192) * H_SZ + ks * 32);
        #pragma unroll
        for (int q = 0; q < 8; ++q) {
            float4 v;
            v = r0[q]; w0[4*q+0]=v.x; w0[4*q+1]=v.y; w0[4*q+2]=v.z; w0[4*q+3]=v.w;
            v = r1[q]; w1[4*q+0]=v.x; w1[4*q+1]=v.y; w1[4*q+2]=v.z; w1[4*q+3]=v.w;
            v = r2[q]; w2[4*q+0]=v.x; w2[4*q+1]=v.y; w2[4*q+2]=v.z; w2[4*q+3]=v.w;
            v = r3[q]; w3[4*q+0]=v.x; w3[4*q+1]=v.y; w3[4*q+2]=v.z; w3[4*q+3]=v.w;
        }
    }
    const float bj0 = bh[jg +   0];
    const float bj1 = bh[jg +  64];
    const float bj2 = bh[jg + 128];
    const float bj3 = bh[jg + 192];

    // --- init h state (padded layout) ---
    if (tid < H_SZ) {
        hs[0][(tid >> 5) * SLICE_W + (tid & 31)] = h0[(size_t)b * H_SZ + tid];
    }
    __syncthreads();

    float* __restrict__ outb = out + (size_t)b * H_SZ;
    const size_t tstr = (size_t)B_SZ * H_SZ;

    float xp0 = outb[jg +   0];
    float xp1 = outb[jg +  64];
    float xp2 = outb[jg + 128];
    float xp3 = outb[jg + 192];

    float hn0 = 0.f, hn1 = 0.f, hn2 = 0.f, hn3 = 0.f;
    int cur = 0;
    for (int t = 0; t < L_SEQ; ++t) {
        // prefetch next step's xproj (t=L-1 reads the h_final region: in
        // bounds, discarded)
        const size_t nb = (size_t)(t + 1) * tstr;
        float nxp0 = outb[nb + jg +   0];
        float nxp1 = outb[nb + jg +  64];
        float nxp2 = outb[nb + jg + 128];
        float nxp3 = outb[nb + jg + 192];

        float a0 = 0.f, a1 = 0.f, a2 = 0.f, a3 = 0.f;
        const float4* hv4 = reinterpret_cast<const float4*>(&hs[cur][ks * SLICE_W]);
        #pragma unroll
        for (int q = 0; q < 8; ++q) {
            float4 hv = hv4[q];
            a0 = fmaf(w0[4*q+0], hv.x, a0); a0 = fmaf(w0[4*q+1], hv.y, a0);
            a0 = fmaf(w0[4*q+2], hv.z, a0); a0 = fmaf(w0[4*q+3], hv.w, a0);
            a1 = fmaf(w1[4*q+0], hv.x, a1); a1 = fmaf(w1[4*q+1], hv.y, a1);
            a1 = fmaf(w1[4*q+2], hv.z, a1); a1 = fmaf(w1[4*q+3], hv.w, a1);
            a2 = fmaf(w2[4*q+0], hv.x, a2); a2 = fmaf(w2[4*q+1], hv.y, a2);
            a2 = fmaf(w2[4*q+2], hv.z, a2); a2 = fmaf(w2[4*q+3], hv.w, a2);
            a3 = fmaf(w3[4*q+0], hv.x, a3); a3 = fmaf(w3[4*q+1], hv.y, a3);
            a3 = fmaf(w3[4*q+2], hv.z, a3); a3 = fmaf(w3[4*q+3], hv.w, a3);
        }
        a0 = red8(a0); a1 = red8(a1); a2 = red8(a2); a3 = red8(a3);

        hn0 = fast_tanh(xp0 + bj0 + a0);
        hn1 = fast_tanh(xp1 + bj1 + a1);
        hn2 = fast_tanh(xp2 + bj2 + a2);
        hn3 = fast_tanh(xp3 + bj3 + a3);

        if (ks == 0) {
            const size_t tb = (size_t)t * tstr;
            outb[tb + jg +   0] = hn0;
            outb[tb + jg +  64] = hn1;
            outb[tb + jg + 128] = hn2;
            outb[tb + jg + 192] = hn3;
            float* hw = hs[cur ^ 1];
            const int base = (jg >> 5) * SLICE_W + (jg & 31);
            hw[base + 0 * (2 * SLICE_W)] = hn0;
            hw[base + 1 * (2 * SLICE_W)] = hn1;
            hw[base + 2 * (2 * SLICE_W)] = hn2;
            hw[base + 3 * (2 * SLICE_W)] = hn3;
        }
        __syncthreads();
        cur ^= 1;
        xp0 = nxp0; xp1 = nxp1; xp2 = nxp2; xp3 = nxp3;
    }

    if (ks == 0) {
        float* hf = out + (size_t)L_SEQ * tstr + (size_t)b * H_SZ;
        hf[jg +   0] = hn0;
        hf[jg +  64] = hn1;
        hf[jg + 128] = hn2;
        hf[jg + 192] = hn3;
    }
}

extern "C" void kernel_launch(void* const* d_in, const int* in_sizes, int n_in,
                              void* d_out, int out_size, void* d_ws, size_t ws_size,
                              hipStream_t stream) {
    const float* x    = (const float*)d_in[0];   // [L,B,D]
    const float* h0   = (const float*)d_in[1];   // [B,H]
    const float* Wx_w = (const float*)d_in[2];   // [H,D]
    const float* Wx_b = (const float*)d_in[3];   // [H]
    const float* Wh_w = (const float*)d_in[4];   // [H,H]
    const float* Wh_b = (const float*)d_in[5];   // [H]
    float* out = (float*)d_out;                  // [L,B,H] ++ [B,H]

    (void)in_sizes; (void)n_in; (void)d_ws; (void)ws_size; (void)out_size;

    dim3 grid1((L_SEQ * B_SZ) / 128, H_SZ / 128);
    xproj_gemm<<<grid1, 256, 0, stream>>>(x, Wx_w, Wx_b, out);

    rnn_scan<<<dim3(B_SZ), 512, 0, stream>>>(h0, Wh_w, Wh_b, out);
}

// Round 5
// 1120.407 us; speedup vs baseline: 2.5078x; 1.0018x over previous
//
#include <hip/hip_runtime.h>
#include <cstddef>

#define L_SEQ 1024
#define B_SZ  128
#define D_SZ  256
#define H_SZ  256

// ---------------------------------------------------------------------------
// Kernel 1: xproj GEMM (unchanged from R3 -- control)
// ---------------------------------------------------------------------------
#define KT  16
#define LDA 132

__global__ __launch_bounds__(256) void xproj_gemm(
    const float* __restrict__ x, const float* __restrict__ Wx,
    const float* __restrict__ bx, float* __restrict__ out)
{
    __shared__ float sA[KT][LDA];
    __shared__ float sB[KT][LDA];

    const int tm  = blockIdx.x;
    const int tn  = blockIdx.y;
    const int tid = threadIdx.x;
    const int tx  = tid & 15;
    const int ty  = tid >> 4;
    const int srow = tid >> 2;
    const int skq  = tid & 3;

    const float* __restrict__ Ag = x  + (size_t)(tm * 128 + srow) * D_SZ + skq * 4;
    const float* __restrict__ Bg = Wx + (size_t)(tn * 128 + srow) * D_SZ + skq * 4;

    float c[2][2][4][4];
    #pragma unroll
    for (int mc = 0; mc < 2; ++mc)
        #pragma unroll
        for (int nc = 0; nc < 2; ++nc)
            #pragma unroll
            for (int i = 0; i < 4; ++i)
                #pragma unroll
                for (int j = 0; j < 4; ++j) c[mc][nc][i][j] = 0.0f;

    for (int kt = 0; kt < D_SZ / KT; ++kt) {
        float4 av0 = *reinterpret_cast<const float4*>(Ag + kt * KT);
        float4 av1 = *reinterpret_cast<const float4*>(Ag + (size_t)64 * D_SZ + kt * KT);
        float4 bv0 = *reinterpret_cast<const float4*>(Bg + kt * KT);
        float4 bv1 = *reinterpret_cast<const float4*>(Bg + (size_t)64 * D_SZ + kt * KT);
        __syncthreads();
        sA[skq * 4 + 0][srow] = av0.x; sA[skq * 4 + 1][srow] = av0.y;
        sA[skq * 4 + 2][srow] = av0.z; sA[skq * 4 + 3][srow] = av0.w;
        sA[skq * 4 + 0][64 + srow] = av1.x; sA[skq * 4 + 1][64 + srow] = av1.y;
        sA[skq * 4 + 2][64 + srow] = av1.z; sA[skq * 4 + 3][64 + srow] = av1.w;
        sB[skq * 4 + 0][srow] = bv0.x; sB[skq * 4 + 1][srow] = bv0.y;
        sB[skq * 4 + 2][srow] = bv0.z; sB[skq * 4 + 3][srow] = bv0.w;
        sB[skq * 4 + 0][64 + srow] = bv1.x; sB[skq * 4 + 1][64 + srow] = bv1.y;
        sB[skq * 4 + 2][64 + srow] = bv1.z; sB[skq * 4 + 3][64 + srow] = bv1.w;
        __syncthreads();
        #pragma unroll
        for (int kk = 0; kk < KT; ++kk) {
            float4 am0 = *reinterpret_cast<const float4*>(&sA[kk][ty * 4]);
            float4 am1 = *reinterpret_cast<const float4*>(&sA[kk][64 + ty * 4]);
            float4 bn0 = *reinterpret_cast<const float4*>(&sB[kk][tx * 4]);
            float4 bn1 = *reinterpret_cast<const float4*>(&sB[kk][64 + tx * 4]);
            float aa[2][4] = {{am0.x, am0.y, am0.z, am0.w}, {am1.x, am1.y, am1.z, am1.w}};
            float bb[2][4] = {{bn0.x, bn0.y, bn0.z, bn0.w}, {bn1.x, bn1.y, bn1.z, bn1.w}};
            #pragma unroll
            for (int mc = 0; mc < 2; ++mc)
                #pragma unroll
                for (int nc = 0; nc < 2; ++nc)
                    #pragma unroll
                    for (int i = 0; i < 4; ++i)
                        #pragma unroll
                        for (int j = 0; j < 4; ++j)
                            c[mc][nc][i][j] = fmaf(aa[mc][i], bb[nc][j], c[mc][nc][i][j]);
        }
    }

    #pragma unroll
    for (int nc = 0; nc < 2; ++nc) {
        float4 bias = *reinterpret_cast<const float4*>(bx + tn * 128 + nc * 64 + tx * 4);
        #pragma unroll
        for (int mc = 0; mc < 2; ++mc)
            #pragma unroll
            for (int i = 0; i < 4; ++i) {
                float4 v;
                v.x = c[mc][nc][i][0] + bias.x;
                v.y = c[mc][nc][i][1] + bias.y;
                v.z = c[mc][nc][i][2] + bias.z;
                v.w = c[mc][nc][i][3] + bias.w;
                *reinterpret_cast<float4*>(
                    out + (size_t)(tm * 128 + mc * 64 + ty * 4 + i) * H_SZ
                        + tn * 128 + nc * 64 + tx * 4) = v;
            }
    }
}

// ---------------------------------------------------------------------------
// Kernel 2: serial scan, v5 = v4 but with the PROVEN ds_swizzle xor-4
// reduction step (v4's row_ror:4 DPP had the wrong direction: lane i reads
// lane i-4 mod 16 -> cross-group contamination).
// Weights: 64 individual named float2 vars (no arrays -> no
// promote-alloca-to-vector), used via inline-asm v_pk_fma_f32.
// ---------------------------------------------------------------------------
#define SLICE_W 40

typedef float f2 __attribute__((ext_vector_type(2)));

#define PKFMA(acc, w, h) \
    asm("v_pk_fma_f32 %0, %1, %2, %0" : "+v"(acc) : "v"(w), "v"(h))

template <int CTRL>
__device__ __forceinline__ float dpp_add(float v) {
    int y = __builtin_amdgcn_mov_dpp(__float_as_int(v), CTRL, 0xf, 0xf, true);
    return v + __int_as_float(y);
}
__device__ __forceinline__ float swz_xor4_add(float v) {
    int y = __builtin_amdgcn_ds_swizzle(__float_as_int(v), 0x101F); // xor 4
    return v + __int_as_float(y);
}
// Full butterfly over the 8 lanes of a ks-group: valid in every lane.
__device__ __forceinline__ float red8(f2 a) {
    float v = a.x + a.y;
    v = dpp_add<0xB1>(v);    // quad_perm [1,0,3,2]  (xor 1)
    v = dpp_add<0x4E>(v);    // quad_perm [2,3,0,1]  (xor 2)
    v = swz_xor4_add(v);     // xor 4 across quads (proven in R2/R3)
    return v;
}
__device__ __forceinline__ float fast_tanh(float x) {
    float e = __expf(2.0f * x);
    return 1.0f - 2.0f * __builtin_amdgcn_rcpf(e + 1.0f);
}

// weight decls: w{c}_{q}l = pairs [2q], w{c}_{q}h = pairs [2q+1]
#define DECLQ(c, q) \
    f2 w##c##_##q##l = r##c[2 * (q)], w##c##_##q##h = r##c[2 * (q) + 1];
#define DECLC(c) \
    DECLQ(c,0) DECLQ(c,1) DECLQ(c,2) DECLQ(c,3) \
    DECLQ(c,4) DECLQ(c,5) DECLQ(c,6) DECLQ(c,7)

#define FMAQ(q) { \
    float4 hv = hv4[q]; \
    f2 hlo = {hv.x, hv.y}; \
    f2 hhi = {hv.z, hv.w}; \
    PKFMA(a0, w0_##q##l, hlo); PKFMA(a0, w0_##q##h, hhi); \
    PKFMA(a1, w1_##q##l, hlo); PKFMA(a1, w1_##q##h, hhi); \
    PKFMA(a2, w2_##q##l, hlo); PKFMA(a2, w2_##q##h, hhi); \
    PKFMA(a3, w3_##q##l, hlo); PKFMA(a3, w3_##q##h, hhi); }

__global__ __launch_bounds__(512)
__attribute__((amdgpu_waves_per_eu(2, 2)))
void rnn_scan(
    const float* __restrict__ h0, const float* __restrict__ Wh,
    const float* __restrict__ bh, float* __restrict__ out)
{
    __shared__ __align__(16) float hs[2][8 * SLICE_W];

    const int b    = blockIdx.x;
    const int tid  = threadIdx.x;
    const int lane = tid & 63;
    const int wave = tid >> 6;
    const int ks   = lane & 7;                 // K slice 0..7
    const int jg   = wave * 8 + (lane >> 3);   // channel group 0..63

    const f2* r0 = reinterpret_cast<const f2*>(Wh + (size_t)(jg +   0) * H_SZ + ks * 32);
    const f2* r1 = reinterpret_cast<const f2*>(Wh + (size_t)(jg +  64) * H_SZ + ks * 32);
    const f2* r2 = reinterpret_cast<const f2*>(Wh + (size_t)(jg + 128) * H_SZ + ks * 32);
    const f2* r3 = reinterpret_cast<const f2*>(Wh + (size_t)(jg + 192) * H_SZ + ks * 32);
    DECLC(0) DECLC(1) DECLC(2) DECLC(3)

    const float bj0 = bh[jg +   0];
    const float bj1 = bh[jg +  64];
    const float bj2 = bh[jg + 128];
    const float bj3 = bh[jg + 192];

    if (tid < H_SZ) {
        hs[0][(tid >> 5) * SLICE_W + (tid & 31)] = h0[(size_t)b * H_SZ + tid];
    }
    __syncthreads();

    float* __restrict__ outb = out + (size_t)b * H_SZ;
    const size_t tstr = (size_t)B_SZ * H_SZ;

    float xp0 = outb[jg +   0];
    float xp1 = outb[jg +  64];
    float xp2 = outb[jg + 128];
    float xp3 = outb[jg + 192];

    float hn0 = 0.f, hn1 = 0.f, hn2 = 0.f, hn3 = 0.f;
    int cur = 0;
    for (int t = 0; t < L_SEQ; ++t) {
        const size_t nb = (size_t)(t + 1) * tstr;
        float nxp0 = outb[nb + jg +   0];
        float nxp1 = outb[nb + jg +  64];
        float nxp2 = outb[nb + jg + 128];
        float nxp3 = outb[nb + jg + 192];

        f2 a0 = {0.f, 0.f}, a1 = {0.f, 0.f}, a2 = {0.f, 0.f}, a3 = {0.f, 0.f};
        const float4* hv4 = reinterpret_cast<const float4*>(&hs[cur][ks * SLICE_W]);
        FMAQ(0) FMAQ(1) FMAQ(2) FMAQ(3) FMAQ(4) FMAQ(5) FMAQ(6) FMAQ(7)

        float s0 = red8(a0);
        float s1 = red8(a1);
        float s2 = red8(a2);
        float s3 = red8(a3);

        hn0 = fast_tanh(xp0 + bj0 + s0);
        hn1 = fast_tanh(xp1 + bj1 + s1);
        hn2 = fast_tanh(xp2 + bj2 + s2);
        hn3 = fast_tanh(xp3 + bj3 + s3);

        if (ks == 0) {
            const size_t tb = (size_t)t * tstr;
            outb[tb + jg +   0] = hn0;
            outb[tb + jg +  64] = hn1;
            outb[tb + jg + 128] = hn2;
            outb[tb + jg + 192] = hn3;
            float* hw = hs[cur ^ 1];
            const int base = (jg >> 5) * SLICE_W + (jg & 31);
            hw[base + 0 * (2 * SLICE_W)] = hn0;
            hw[base + 1 * (2 * SLICE_W)] = hn1;
            hw[base + 2 * (2 * SLICE_W)] = hn2;
            hw[base + 3 * (2 * SLICE_W)] = hn3;
        }
        __syncthreads();
        cur ^= 1;
        xp0 = nxp0; xp1 = nxp1; xp2 = nxp2; xp3 = nxp3;
    }

    if (ks == 0) {
        float* hf = out + (size_t)L_SEQ * tstr + (size_t)b * H_SZ;
        hf[jg +   0] = hn0;
        hf[jg +  64] = hn1;
        hf[jg + 128] = hn2;
        hf[jg + 192] = hn3;
    }
}

extern "C" void kernel_launch(void* const* d_in, const int* in_sizes, int n_in,
                              void* d_out, int out_size, void* d_ws, size_t ws_size,
                              hipStream_t stream) {
    const float* x    = (const float*)d_in[0];   // [L,B,D]
    const float* h0   = (const float*)d_in[1];   // [B,H]
    const float* Wx_w = (const float*)d_in[2];   // [H,D]
    const float* Wx_b = (const float*)d_in[3];   // [H]
    const float* Wh_w = (const float*)d_in[4];   // [H,H]
    const float* Wh_b = (const float*)d_in[5];   // [H]
    float* out = (float*)d_out;                  // [L,B,H] ++ [B,H]

    (void)in_sizes; (void)n_in; (void)d_ws; (void)ws_size; (void)out_size;

    dim3 grid1((L_SEQ * B_SZ) / 128, H_SZ / 128);
    xproj_gemm<<<grid1, 256, 0, stream>>>(x, Wx_w, Wx_b, out);

    rnn_scan<<<dim3(B_SZ), 512, 0, stream>>>(h0, Wh_w, Wh_b, out);
}